// Round 4
// baseline (7637.100 us; speedup 1.0000x reference)
//
#include <hip/hip_runtime.h>

// LSTM b=32, t=1024, din=512, hid=1024. Persistent cooperative kernel:
// 128 blocks x 512 threads (8 waves), each block owns 8 hidden units.
//
// R7: self-tagged data protocol — NO flags, NO producer ack, NO separate
// h-load. h is transmitted as f32 with the step-tag in each word's mantissa
// LSB (2^-23 rel perturbation; word atomicity is HW-guaranteed so no 16B
// tearing assumption). Producer pointwise threads store their own tagged
// word directly (coalesced, 1 instr). Consumers poll the DATA: load all 32
// dwordx4, vmcnt(0), check LSBs, __any-retry. Chain/step drops from ~3.5
// L3 RTs (store+ack, flag, poll, load) to ~1.5 (store visible, poll hit).
//
// Anti-ABA: slot = n&1 ping-pong, tag = (n>>1)&1 -> version space period 4.
// Skew bound: while any block polls v(n), no block can publish beyond
// v(n+1): publishing v(n+2) needs all blocks' v(n+1), which the stuck block
// publishes only after accepting v(n). Slot of v(n+1) != slot of v(n); the
// next write to v(n)'s slot is v(n+2). SAFE. Tags also differ across one
// slot-reuse ((n>>1) increments), double protection.
//
// Poll runs BEFORE barrier C (H waves touch red only post-C), overlapping
// G's pointwise+publish. C only guards red(t) reads vs red(t+1) writes.
// Weights stay register-resident (R6). REDSTR=36 gather layout (R6).

#define T_STEPS 1024
#define BATCH   32
#define DIN     512
#define HID     1024
#define KTOT    1536
#define NBLK    128
#define REDSTR  36            // dword row stride: gather bank = 4*l3+pu -> <=2-way
#define REDW    (32*REDSTR)   // 1152 dwords per slot
#define NSLOT   8
#define HSLOT   (NBLK*256)    // floats per ping-pong slot: [128 blk][32 b][8 u]

typedef __attribute__((ext_vector_type(8))) short  short8;
typedef __attribute__((ext_vector_type(4))) float  floatx4;
typedef __attribute__((ext_vector_type(4))) unsigned int uintx4;
typedef __attribute__((ext_vector_type(4))) unsigned short ushort4_;

#define MFMA16(a,b,c) __builtin_amdgcn_mfma_f32_16x16x32_bf16(a, b, c, 0, 0, 0)

__device__ __forceinline__ unsigned short f2bf(float f) {
    unsigned u = __builtin_bit_cast(unsigned, f);
    u += 0x7FFFu + ((u >> 16) & 1u);
    return (unsigned short)(u >> 16);
}
__device__ __forceinline__ float sigf(float x) { return 1.f / (1.f + __expf(-x)); }
__device__ __forceinline__ float tanh_fast(float x) {
    float e = __expf(2.f * x);
    return 1.f - 2.f / (e + 1.f);
}
// pack 2 f32 -> 2 bf16 in one u32 (RTNE); gfx950 hw instr
__device__ __forceinline__ unsigned cvt2(float a, float b) {
    unsigned r;
    asm("v_cvt_pk_bf16_f32 %0, %1, %2" : "=v"(r) : "v"(a), "v"(b));
    return r;
}

// ---- device-scope (L3 coherence point) access helpers: sc1 ----
__device__ __forceinline__ floatx4 coh_load16f(const void* p) {
    floatx4 v;
    asm volatile("global_load_dwordx4 %0, %1, off sc1" : "=v"(v) : "v"(p));
    return v;
}
__device__ __forceinline__ void coh_store4u(void* p, unsigned v) {
    asm volatile("global_store_dword %0, %1, off sc1" :: "v"(p), "v"(v) : "memory");
}
__device__ __forceinline__ void wait_vm0() {
    asm volatile("s_waitcnt vmcnt(0)" ::: "memory");
}

// ---- prep: kernel [1536][4096] fp32 -> wt [4096 cols][1536 k] bf16 (transposed) ----
__global__ __launch_bounds__(256) void prep_wt(const float* __restrict__ kern,
                                               unsigned short* __restrict__ wt) {
    __shared__ unsigned short tile[64][72];
    const int c0 = (blockIdx.x & 63) * 64;
    const int k0 = (blockIdx.x >> 6) * 64;
    const int cl = threadIdx.x & 63;
    const int kg = threadIdx.x >> 6;
    #pragma unroll
    for (int i = 0; i < 16; ++i) {
        int kl = kg * 16 + i;
        tile[cl][kl] = f2bf(kern[(k0 + kl) * 4096 + c0 + cl]);
    }
    __syncthreads();
    #pragma unroll
    for (int i = 0; i < 16; ++i) {
        int cc = kg * 16 + i;
        wt[(size_t)(c0 + cc) * KTOT + k0 + cl] = tile[cc][cl];
    }
}

// ---- prep: x [32][1024][512] fp32 -> xT [1024][32][512] bf16 ----
__global__ __launch_bounds__(256) void prep_x(const float* __restrict__ x,
                                              unsigned short* __restrict__ xT) {
    const int row = blockIdx.x * 2 + (threadIdx.x >> 7);
    const int l   = threadIdx.x & 127;
    const int b = row >> 10, t = row & 1023;
    float4 v = ((const float4*)(x + (size_t)row * DIN))[l];
    ushort4_ o;
    o.x = f2bf(v.x); o.y = f2bf(v.y); o.z = f2bf(v.z); o.w = f2bf(v.w);
    *(ushort4_*)(xT + ((size_t)t * BATCH + b) * DIN + l * 4) = o;
}

// ---- prep: h0(f32, tag 0) -> slot0; slot1 poisoned stale (LSB=1) ----
__global__ __launch_bounds__(256) void init_h(const float* __restrict__ h_init,
                                              unsigned* __restrict__ hbuf_u) {
    const int p0 = blockIdx.x * 4;           // 32 blocks x 4 producer regions
    const int u = threadIdx.x & 7;
    #pragma unroll
    for (int j = 0; j < 4; ++j) {
        const int p = p0 + j;
        unsigned tv = __builtin_bit_cast(unsigned, h_init[p * 8 + u]) & ~1u;
        hbuf_u[p * 256 + threadIdx.x] = tv;            // v0: slot0, tag 0
        hbuf_u[HSLOT + p * 256 + threadIdx.x] = 1u;    // slot1: stale for v1 (tag0)
    }
}

// ---- persistent LSTM ----
__global__ __launch_bounds__(512, 2) void lstm_persist(
    const unsigned short* __restrict__ wt,   // [4096][1536] bf16
    const unsigned short* __restrict__ xT,   // [1024][32][512] bf16
    float* __restrict__ hbuf,                // [2][128 blk][32 b][8 u] f32 tagged
    const float* __restrict__ bias,          // [4096]
    float* __restrict__ out)                 // [32][1024][1024] fp32
{
    __shared__ float red[NSLOT][REDW];       // 36,864 B

    const int bk   = blockIdx.x;
    const int tid  = threadIdx.x;
    const int wave = tid >> 6;
    const int lane = tid & 63;
    const int lrow = lane & 15;
    const int kq   = lane >> 4;
    const bool isG = wave < 4;
    const int  sl  = wave & 3;

    unsigned* hbuf_u = (unsigned*)hbuf;

    // ---- persistent weight fragments in registers (constant across t) ----
    short8 wb[8][2];
    if (isG) {
        #pragma unroll
        for (int i = 0; i < 4; ++i) {
            const int k = sl * 128 + i * 32 + kq * 8;
            #pragma unroll
            for (int c = 0; c < 2; ++c) {
                const int cl = lrow + c * 16;
                const int gcol = (cl >> 3) * HID + bk * 8 + (cl & 7);
                wb[i][c] = *(const short8*)(wt + (size_t)gcol * KTOT + k);
            }
        }
    } else {
        #pragma unroll
        for (int i = 0; i < 8; ++i) {
            const int k = 512 + sl * 256 + i * 32 + kq * 8;
            #pragma unroll
            for (int c = 0; c < 2; ++c) {
                const int cl = lrow + c * 16;
                const int gcol = (cl >> 3) * HID + bk * 8 + (cl & 7);
                wb[i][c] = *(const short8*)(wt + (size_t)gcol * KTOT + k);
            }
        }
    }

    // pointwise mapping (tid<256 <=> G waves): (batch pb, unit pu)
    const int pb = tid >> 3;
    const int pu = tid & 7;
    float bias_r[4];
    float c_state = 0.f;
    if (tid < 256) {
        #pragma unroll
        for (int g = 0; g < 4; ++g) bias_r[g] = bias[g * HID + bk * 8 + pu];
    }

    floatx4 xa[4][2];

    // ---- prologue: red slots for t=0 ----
    {
        const floatx4 zero = {0.f, 0.f, 0.f, 0.f};
        floatx4 acc[2][2] = {{zero, zero}, {zero, zero}};
        if (isG) {
            const unsigned short* xb = xT;   // t = 0
            #pragma unroll
            for (int i = 0; i < 4; ++i) {
                const int k = sl * 128 + i * 32 + kq * 8;
                short8 a0 = *(const short8*)(xb + lrow * DIN + k);
                short8 a1 = *(const short8*)(xb + (lrow + 16) * DIN + k);
                acc[0][0] = MFMA16(a0, wb[i][0], acc[0][0]);
                acc[0][1] = MFMA16(a0, wb[i][1], acc[0][1]);
                acc[1][0] = MFMA16(a1, wb[i][0], acc[1][0]);
                acc[1][1] = MFMA16(a1, wb[i][1], acc[1][1]);
            }
            const unsigned short* xn = xT + (size_t)1 * (BATCH * DIN);
            #pragma unroll
            for (int i = 0; i < 4; ++i) {
                const int k = sl * 128 + i * 32 + kq * 8;
                xa[i][0] = *(const floatx4*)(xn + lrow * DIN + k);
                xa[i][1] = *(const floatx4*)(xn + (lrow + 16) * DIN + k);
            }
        } else {
            // v0 guaranteed by init_h: load (sc1), no check needed
            floatx4 hf[8][2][2];
            #pragma unroll
            for (int i = 0; i < 8; ++i) {
                const int p = sl * 32 + i * 4 + kq;
                #pragma unroll
                for (int c = 0; c < 2; ++c) {
                    const float* src = hbuf + p * 256 + (lrow + c * 16) * 8;
                    hf[i][c][0] = coh_load16f(src);
                    hf[i][c][1] = coh_load16f(src + 4);
                }
            }
            wait_vm0();
            __builtin_amdgcn_sched_barrier(0);
            #pragma unroll
            for (int i = 0; i < 8; ++i) {
                union { short8 s; unsigned u[4]; } wa[2];
                #pragma unroll
                for (int c = 0; c < 2; ++c) {
                    wa[c].u[0] = cvt2(hf[i][c][0][0], hf[i][c][0][1]);
                    wa[c].u[1] = cvt2(hf[i][c][0][2], hf[i][c][0][3]);
                    wa[c].u[2] = cvt2(hf[i][c][1][0], hf[i][c][1][1]);
                    wa[c].u[3] = cvt2(hf[i][c][1][2], hf[i][c][1][3]);
                }
                acc[0][0] = MFMA16(wa[0].s, wb[i][0], acc[0][0]);
                acc[0][1] = MFMA16(wa[0].s, wb[i][1], acc[0][1]);
                acc[1][0] = MFMA16(wa[1].s, wb[i][0], acc[1][0]);
                acc[1][1] = MFMA16(wa[1].s, wb[i][1], acc[1][1]);
            }
        }
        #pragma unroll
        for (int mt = 0; mt < 2; ++mt)
            #pragma unroll
            for (int nt = 0; nt < 2; ++nt)
                #pragma unroll
                for (int r = 0; r < 4; ++r)
                    red[wave][(mt * 16 + kq * 4 + r) * REDSTR + nt * 16 + lrow]
                        = acc[mt][nt][r];
    }

    for (int t = 0; t < T_STEPS; ++t) {
        __syncthreads();    // A(t): red slots for t complete

        const unsigned tg = ((unsigned)(t + 1) >> 1) & 1u;   // tag of version t+1
        const size_t   so = (size_t)((t + 1) & 1) * HSLOT;   // slot of version t+1

        const floatx4 zero = {0.f, 0.f, 0.f, 0.f};
        floatx4 acc[2][2] = {{zero, zero}, {zero, zero}};

        if (tid < 256) {
            // ---- G: gather gates, pointwise, tagged publish, out, x-MFMA ----
            float gv[4];
            #pragma unroll
            for (int g = 0; g < 4; ++g) {
                float s = bias_r[g];
                #pragma unroll
                for (int w = 0; w < NSLOT; ++w)
                    s += red[w][pb * REDSTR + g * 8 + pu];
                gv[g] = s;
            }
            const float fg = sigf(gv[0]);
            const float ig = sigf(gv[1]);
            const float og = sigf(gv[2]);
            const float gg = tanh_fast(gv[3]);
            c_state = fg * c_state + ig * gg;
            const float hn = og * tanh_fast(c_state);

            if (t + 1 < T_STEPS) {
                // publish: per-thread tagged f32, coalesced 256B/wave, no ack
                unsigned hv = (__builtin_bit_cast(unsigned, hn) & ~1u) | tg;
                coh_store4u(hbuf_u + so + bk * 256 + tid, hv);
            }
            out[(size_t)pb * (T_STEPS * HID) + (size_t)t * HID + bk * 8 + pu] = hn;

            if (t + 1 < T_STEPS) {
                // x-part of gates(t+1) from prefetched regs
                #pragma unroll
                for (int i = 0; i < 4; ++i) {
                    short8 a0 = __builtin_bit_cast(short8, xa[i][0]);
                    short8 a1 = __builtin_bit_cast(short8, xa[i][1]);
                    acc[0][0] = MFMA16(a0, wb[i][0], acc[0][0]);
                    acc[0][1] = MFMA16(a0, wb[i][1], acc[0][1]);
                    acc[1][0] = MFMA16(a1, wb[i][0], acc[1][0]);
                    acc[1][1] = MFMA16(a1, wb[i][1], acc[1][1]);
                }
                if (t + 2 < T_STEPS) {
                    const unsigned short* xn = xT + (size_t)(t + 2) * (BATCH * DIN);
                    #pragma unroll
                    for (int i = 0; i < 4; ++i) {
                        const int k = sl * 128 + i * 32 + kq * 8;
                        xa[i][0] = *(const floatx4*)(xn + lrow * DIN + k);
                        xa[i][1] = *(const floatx4*)(xn + (lrow + 16) * DIN + k);
                    }
                }
            }
        } else if (t + 1 < T_STEPS) {
            // ---- H: poll the DATA for version t+1 (pre-C; overlaps G) ----
            const float* hb = hbuf + so;
            floatx4 hf[8][2][2];
            while (true) {
                #pragma unroll
                for (int i = 0; i < 8; ++i) {
                    const int p = sl * 32 + i * 4 + kq;
                    #pragma unroll
                    for (int c = 0; c < 2; ++c) {
                        const float* src = hb + p * 256 + (lrow + c * 16) * 8;
                        hf[i][c][0] = coh_load16f(src);
                        hf[i][c][1] = coh_load16f(src + 4);
                    }
                }
                wait_vm0();
                __builtin_amdgcn_sched_barrier(0);
                unsigned od = 0;
                #pragma unroll
                for (int i = 0; i < 8; ++i)
                    #pragma unroll
                    for (int c = 0; c < 2; ++c)
                        #pragma unroll
                        for (int h2 = 0; h2 < 2; ++h2) {
                            uintx4 u = __builtin_bit_cast(uintx4, hf[i][c][h2]);
                            od |= u[0] ^ tg; od |= u[1] ^ tg;
                            od |= u[2] ^ tg; od |= u[3] ^ tg;
                        }
                if (!__any((int)(od & 1u))) break;   // all words fresh, all lanes
                __builtin_amdgcn_s_sleep(1);
            }
            // convert + h-part MFMA (frees hf progressively)
            #pragma unroll
            for (int i = 0; i < 8; ++i) {
                union { short8 s; unsigned u[4]; } wa[2];
                #pragma unroll
                for (int c = 0; c < 2; ++c) {
                    wa[c].u[0] = cvt2(hf[i][c][0][0], hf[i][c][0][1]);
                    wa[c].u[1] = cvt2(hf[i][c][0][2], hf[i][c][0][3]);
                    wa[c].u[2] = cvt2(hf[i][c][1][0], hf[i][c][1][1]);
                    wa[c].u[3] = cvt2(hf[i][c][1][2], hf[i][c][1][3]);
                }
                acc[0][0] = MFMA16(wa[0].s, wb[i][0], acc[0][0]);
                acc[0][1] = MFMA16(wa[0].s, wb[i][1], acc[0][1]);
                acc[1][0] = MFMA16(wa[1].s, wb[i][0], acc[1][0]);
                acc[1][1] = MFMA16(wa[1].s, wb[i][1], acc[1][1]);
            }
        }

        if (t + 1 == T_STEPS) break;   // uniform
        __syncthreads();    // C(t): G's red(t) reads done -> slots reusable

        #pragma unroll
        for (int mt = 0; mt < 2; ++mt)
            #pragma unroll
            for (int nt = 0; nt < 2; ++nt)
                #pragma unroll
                for (int r = 0; r < 4; ++r)
                    red[wave][(mt * 16 + kq * 4 + r) * REDSTR + nt * 16 + lrow]
                        = acc[mt][nt][r];
    }
}

extern "C" void kernel_launch(void* const* d_in, const int* in_sizes, int n_in,
                              void* d_out, int out_size, void* d_ws, size_t ws_size,
                              hipStream_t stream) {
    (void)in_sizes; (void)n_in; (void)out_size;
    const float* x      = (const float*)d_in[0];
    // d_in[1] = input_paddings (all zero, unused per reference)
    const float* kern   = (const float*)d_in[2];
    const float* bias   = (const float*)d_in[3];
    const float* h_init = (const float*)d_in[4];
    float* out = (float*)d_out;

    char* ws = (char*)d_ws;
    unsigned short* wt   = (unsigned short*)(ws);                       // 12,582,912 B
    unsigned short* xT   = (unsigned short*)(ws + 12582912);            // 33,554,432 B
    float*          hbuf = (float*)(ws + 12582912 + 33554432);          //    262,144 B
    (void)ws_size;

    prep_wt<<<dim3(64 * 24), dim3(256), 0, stream>>>(kern, wt);
    prep_x<<<dim3(BATCH * T_STEPS / 2), dim3(256), 0, stream>>>(x, xT);
    init_h<<<dim3(32), dim3(256), 0, stream>>>(h_init, (unsigned*)hbuf);

    void* args[] = { &wt, &xT, &hbuf, &bias, &out };
    hipLaunchCooperativeKernel((const void*)lstm_persist, dim3(NBLK), dim3(512),
                               args, 0, stream);
}

// Round 5
// 5227.094 us; speedup vs baseline: 1.4611x; 1.4611x over previous
//
#include <hip/hip_runtime.h>

// LSTM b=32, t=1024, din=512, hid=1024. Persistent cooperative kernel.
//
// R8: batch-split all-to-all + tagged-data transport + selective re-read.
//  - 128 blocks = 2 independent 64-block systems (batch halves of 16).
//    Block (p,ug) owns 16 batches x 16 units (64 gate cols), M=16 MFMA.
//    Consumers read h only for their half: 64KB/block -> 8MB/step total
//    (== R6's bf16 traffic; R7's 16-48MB/step was the regression cause).
//  - h transported as f32 with step-tag in each word's mantissa LSB
//    (2^-23 rel; invisible after bf16 cvt). Publish = ONE sc1 store per
//    pointwise thread. No flags, no producer ack, no separate h-load.
//  - Consumer poll = the data load itself; per-16B-chunk freshness mask,
//    re-read ONLY stale chunks (R7 re-read everything every round).
//    Each wave's 8 chunks depend on just 8 producer blocks.
//  - ONE barrier/step: red is ping-pong [2][8 slots][16x68] f32 in LDS.
//  - Same-address publish ordering: wait_vm0 before each publish (free in
//    steady state; poll's vmcnt(0) already drained priors).
//  - ABA: slot=n&1, tag=(n>>1)&1. While any block polls v(n), no producer
//    of its system can publish v(n+2) (needs all v(n+1), needs the slow
//    block's v(n+1), which follows its v(n) accept). Slot of v(n+1) is the
//    other slot; v(n-2) in this slot has the other tag. Safe.

#define T_STEPS 1024
#define BATCH   32
#define DIN     512
#define HID     1024
#define KTOT    1536
#define NBLK    128
#define RSTR    68            // f32 row stride in red (64 cols + 4 pad)
#define REDW    (16*RSTR)     // 1088 floats per wave slot
#define NSLOT   8
#define HSLOT   32768         // f32 words per slot: [32 batch rows][1024 units]

typedef __attribute__((ext_vector_type(8))) short  short8;
typedef __attribute__((ext_vector_type(4))) float  floatx4;
typedef __attribute__((ext_vector_type(4))) unsigned int uintx4;
typedef __attribute__((ext_vector_type(4))) unsigned short ushort4_;

#define MFMA16(a,b,c) __builtin_amdgcn_mfma_f32_16x16x32_bf16(a, b, c, 0, 0, 0)

__device__ __forceinline__ unsigned short f2bf(float f) {
    unsigned u = __builtin_bit_cast(unsigned, f);
    u += 0x7FFFu + ((u >> 16) & 1u);
    return (unsigned short)(u >> 16);
}
__device__ __forceinline__ float sigf(float x) { return 1.f / (1.f + __expf(-x)); }
__device__ __forceinline__ float tanh_fast(float x) {
    float e = __expf(2.f * x);
    return 1.f - 2.f / (e + 1.f);
}
// pack 2 f32 -> 2 bf16 in one u32 (RTNE); gfx950 hw instr
__device__ __forceinline__ unsigned cvt2(float a, float b) {
    unsigned r;
    asm("v_cvt_pk_bf16_f32 %0, %1, %2" : "=v"(r) : "v"(a), "v"(b));
    return r;
}

// ---- device-scope (L3 coherence point) access helpers: sc1 ----
__device__ __forceinline__ floatx4 coh_load16f(const void* p) {
    floatx4 v;
    asm volatile("global_load_dwordx4 %0, %1, off sc1" : "=v"(v) : "v"(p));
    return v;
}
__device__ __forceinline__ void coh_store4u(void* p, unsigned v) {
    asm volatile("global_store_dword %0, %1, off sc1" :: "v"(p), "v"(v) : "memory");
}
__device__ __forceinline__ void wait_vm0() {
    asm volatile("s_waitcnt vmcnt(0)" ::: "memory");
}

// ---- prep: kernel [1536][4096] fp32 -> wt [4096 cols][1536 k] bf16 ----
__global__ __launch_bounds__(256) void prep_wt(const float* __restrict__ kern,
                                               unsigned short* __restrict__ wt) {
    __shared__ unsigned short tile[64][72];
    const int c0 = (blockIdx.x & 63) * 64;
    const int k0 = (blockIdx.x >> 6) * 64;
    const int cl = threadIdx.x & 63;
    const int kg = threadIdx.x >> 6;
    #pragma unroll
    for (int i = 0; i < 16; ++i) {
        int kl = kg * 16 + i;
        tile[cl][kl] = f2bf(kern[(k0 + kl) * 4096 + c0 + cl]);
    }
    __syncthreads();
    #pragma unroll
    for (int i = 0; i < 16; ++i) {
        int cc = kg * 16 + i;
        wt[(size_t)(c0 + cc) * KTOT + k0 + cl] = tile[cc][cl];
    }
}

// ---- prep: x [32][1024][512] fp32 -> xT [1024][32][512] bf16 ----
__global__ __launch_bounds__(256) void prep_x(const float* __restrict__ x,
                                              unsigned short* __restrict__ xT) {
    const int row = blockIdx.x * 2 + (threadIdx.x >> 7);
    const int l   = threadIdx.x & 127;
    const int b = row >> 10, t = row & 1023;
    float4 v = ((const float4*)(x + (size_t)row * DIN))[l];
    ushort4_ o;
    o.x = f2bf(v.x); o.y = f2bf(v.y); o.z = f2bf(v.z); o.w = f2bf(v.w);
    *(ushort4_*)(xT + ((size_t)t * BATCH + b) * DIN + l * 4) = o;
}

// ---- prep: h0(f32, tag0) -> slot0 rows [32][1024]; slot1 poisoned stale ----
__global__ __launch_bounds__(256) void init_h(const float* __restrict__ h_init,
                                              unsigned* __restrict__ hbuf_u) {
    const int idx = blockIdx.x * 256 + threadIdx.x;   // 0..32767
    const int uu = idx & 1023;
    hbuf_u[idx] = __builtin_bit_cast(unsigned, h_init[uu]) & ~1u;  // v0 tag0
    hbuf_u[HSLOT + idx] = 1u;                                      // stale for v1
}

// ---- persistent LSTM ----
__global__ __launch_bounds__(512, 2) void lstm_persist(
    const unsigned short* __restrict__ wt,   // [4096 cols][1536 k] bf16
    const unsigned short* __restrict__ xT,   // [1024][32][512] bf16
    float* __restrict__ hbuf,                // [2][32][1024] f32 tagged
    const float* __restrict__ bias,          // [4096]
    float* __restrict__ out)                 // [32][1024][1024] fp32
{
    __shared__ float red[2][NSLOT][REDW];    // 69,632 B ping-pong accumulators

    const int bk   = blockIdx.x;
    const int p    = bk >> 6;      // batch half (independent system)
    const int ug   = bk & 63;      // unit group: units [ug*16, ug*16+16)
    const int tid  = threadIdx.x;
    const int w    = tid >> 6;     // wave 0..7: k-slice owner
    const int lane = tid & 63;
    const int lrow = lane & 15;
    const int kq   = lane >> 4;

    unsigned* hbuf_u = (unsigned*)hbuf;

    // ---- persistent weights in registers: n-frag nf IS gate nf, unit=lrow ----
    short8 wbx[2][4], wbh[4][4];
    #pragma unroll
    for (int nf = 0; nf < 4; ++nf) {
        const size_t gcol = (size_t)(nf * HID + ug * 16 + lrow) * KTOT;
        #pragma unroll
        for (int i = 0; i < 2; ++i)
            wbx[i][nf] = *(const short8*)(wt + gcol + w * 64 + i * 32 + kq * 8);
        #pragma unroll
        for (int j = 0; j < 4; ++j)
            wbh[j][nf] = *(const short8*)(wt + gcol + 512 + w * 128 + j * 32 + kq * 8);
    }

    // pointwise mapping (tid<256): batch pb (0..15), unit pu (0..15)
    const int pb = tid >> 4;
    const int pu = tid & 15;
    float bias_r[4], c_state = 0.f;
    if (tid < 256) {
        #pragma unroll
        for (int g = 0; g < 4; ++g) bias_r[g] = bias[g * HID + ug * 16 + pu];
    }

    // per-lane h source offset within a slot: row (p*16+lrow), k = w*128+kq*8
    const int hoff = (p * 16 + lrow) * HID + w * 128 + kq * 8;

    floatx4 xa[2];

    // ---- prologue: gates(0) -> red[0]; prefetch x(1) ----
    {
        const floatx4 zero = {0.f, 0.f, 0.f, 0.f};
        floatx4 acc[4] = {zero, zero, zero, zero};
        const unsigned short* xb = xT + (size_t)(p * 16 + lrow) * DIN;  // t=0
        #pragma unroll
        for (int i = 0; i < 2; ++i) {
            short8 a = *(const short8*)(xb + w * 64 + i * 32 + kq * 8);
            #pragma unroll
            for (int nf = 0; nf < 4; ++nf) acc[nf] = MFMA16(a, wbx[i][nf], acc[nf]);
        }
        const unsigned short* xn = xT + ((size_t)1 * BATCH + p * 16 + lrow) * DIN;
        #pragma unroll
        for (int i = 0; i < 2; ++i)
            xa[i] = *(const floatx4*)(xn + w * 64 + i * 32 + kq * 8);

        // v0 guaranteed fresh by init_h (kernel-boundary coherence)
        floatx4 hf[4][2];
        #pragma unroll
        for (int j = 0; j < 4; ++j) {
            hf[j][0] = coh_load16f(hbuf + hoff + j * 32);
            hf[j][1] = coh_load16f(hbuf + hoff + j * 32 + 4);
        }
        wait_vm0();
        __builtin_amdgcn_sched_barrier(0);
        #pragma unroll
        for (int j = 0; j < 4; ++j) {
            union { short8 s; unsigned u[4]; } wa;
            wa.u[0] = cvt2(hf[j][0][0], hf[j][0][1]);
            wa.u[1] = cvt2(hf[j][0][2], hf[j][0][3]);
            wa.u[2] = cvt2(hf[j][1][0], hf[j][1][1]);
            wa.u[3] = cvt2(hf[j][1][2], hf[j][1][3]);
            #pragma unroll
            for (int nf = 0; nf < 4; ++nf) acc[nf] = MFMA16(wa.s, wbh[j][nf], acc[nf]);
        }
        #pragma unroll
        for (int nf = 0; nf < 4; ++nf)
            #pragma unroll
            for (int r = 0; r < 4; ++r)
                red[0][w][(kq * 4 + r) * RSTR + nf * 16 + lrow] = acc[nf][r];
    }

    for (int t = 0; t < T_STEPS; ++t) {
        __syncthreads();    // A(t): red[t&1] complete (the only barrier/step)

        const float* rc = &red[t & 1][0][0];
        float*       rn = &red[(t + 1) & 1][0][0];
        const unsigned tg = ((unsigned)(t + 1) >> 1) & 1u;  // tag of v(t+1)
        const int      so = ((t + 1) & 1) * HSLOT;          // slot of v(t+1)

        if (tid < 256) {
            // ---- pointwise: gather 8 slots x 4 gates, activate, publish ----
            float gv[4];
            #pragma unroll
            for (int g = 0; g < 4; ++g) {
                float s = bias_r[g];
                #pragma unroll
                for (int wv = 0; wv < NSLOT; ++wv)
                    s += rc[wv * REDW + pb * RSTR + g * 16 + pu];
                gv[g] = s;
            }
            const float fg = sigf(gv[0]);
            const float ig = sigf(gv[1]);
            const float og = sigf(gv[2]);
            const float gg = tanh_fast(gv[3]);
            c_state = fg * c_state + ig * gg;
            const float hn = og * tanh_fast(c_state);

            if (t + 1 < T_STEPS) {
                wait_vm0();   // prior same-address publish drained (ordering)
                unsigned hv = (__builtin_bit_cast(unsigned, hn) & ~1u) | tg;
                coh_store4u(hbuf_u + so + (p * 16 + pb) * HID + ug * 16 + pu, hv);
            }
            out[(size_t)(p * 16 + pb) * (T_STEPS * HID) + (size_t)t * HID
                + ug * 16 + pu] = hn;
        }

        if (t + 1 == T_STEPS) break;   // uniform

        // ---- ALL waves: x-part MFMA for gates(t+1) from prefetched regs ----
        const floatx4 zero = {0.f, 0.f, 0.f, 0.f};
        floatx4 acc[4] = {zero, zero, zero, zero};
        #pragma unroll
        for (int i = 0; i < 2; ++i) {
            short8 a = __builtin_bit_cast(short8, xa[i]);
            #pragma unroll
            for (int nf = 0; nf < 4; ++nf) acc[nf] = MFMA16(a, wbx[i][nf], acc[nf]);
        }
        if (t + 2 < T_STEPS) {
            const unsigned short* xn = xT + ((size_t)(t + 2) * BATCH + p * 16 + lrow) * DIN;
            #pragma unroll
            for (int i = 0; i < 2; ++i)
                xa[i] = *(const floatx4*)(xn + w * 64 + i * 32 + kq * 8);
        }

        // ---- poll v(t+1): tagged data IS the handshake; selective re-read ----
        if (tid >= 256) __builtin_amdgcn_s_sleep(12);  // align round 1 ~ publish
        const float* hb = hbuf + so + hoff;
        floatx4 hf[4][2];
        #pragma unroll
        for (int j = 0; j < 4; ++j) {
            hf[j][0] = coh_load16f(hb + j * 32);
            hf[j][1] = coh_load16f(hb + j * 32 + 4);
        }
        wait_vm0();
        __builtin_amdgcn_sched_barrier(0);
        unsigned stale = 0;
        #pragma unroll
        for (int j = 0; j < 4; ++j)
            #pragma unroll
            for (int c2 = 0; c2 < 2; ++c2) {
                uintx4 u = __builtin_bit_cast(uintx4, hf[j][c2]);
                unsigned fr = tg ? (u[0] & u[1] & u[2] & u[3])
                                 : ~(u[0] | u[1] | u[2] | u[3]);
                if (!(fr & 1u)) stale |= 1u << (j * 2 + c2);
            }
        while (__any((int)(stale != 0u))) {
            if (__all((int)(stale == 0xFFu)))
                __builtin_amdgcn_s_sleep(8);   // fully early: back off
            #pragma unroll
            for (int j = 0; j < 4; ++j)
                #pragma unroll
                for (int c2 = 0; c2 < 2; ++c2)
                    if (stale & (1u << (j * 2 + c2)))
                        hf[j][c2] = coh_load16f(hb + j * 32 + c2 * 4);
            wait_vm0();
            __builtin_amdgcn_sched_barrier(0);
            unsigned ns = 0;
            #pragma unroll
            for (int j = 0; j < 4; ++j)
                #pragma unroll
                for (int c2 = 0; c2 < 2; ++c2)
                    if (stale & (1u << (j * 2 + c2))) {
                        uintx4 u = __builtin_bit_cast(uintx4, hf[j][c2]);
                        unsigned fr = tg ? (u[0] & u[1] & u[2] & u[3])
                                         : ~(u[0] | u[1] | u[2] | u[3]);
                        if (!(fr & 1u)) ns |= 1u << (j * 2 + c2);
                    }
            stale = ns;
        }

        // ---- cvt + h-part MFMA ----
        #pragma unroll
        for (int j = 0; j < 4; ++j) {
            union { short8 s; unsigned u[4]; } wa;
            wa.u[0] = cvt2(hf[j][0][0], hf[j][0][1]);
            wa.u[1] = cvt2(hf[j][0][2], hf[j][0][3]);
            wa.u[2] = cvt2(hf[j][1][0], hf[j][1][1]);
            wa.u[3] = cvt2(hf[j][1][2], hf[j][1][3]);
            #pragma unroll
            for (int nf = 0; nf < 4; ++nf) acc[nf] = MFMA16(wa.s, wbh[j][nf], acc[nf]);
        }

        // ---- red writes for t+1 (ping-pong buffer; guarded by A(t+1)) ----
        #pragma unroll
        for (int nf = 0; nf < 4; ++nf)
            #pragma unroll
            for (int r = 0; r < 4; ++r)
                rn[w * REDW + (kq * 4 + r) * RSTR + nf * 16 + lrow] = acc[nf][r];
    }
}

extern "C" void kernel_launch(void* const* d_in, const int* in_sizes, int n_in,
                              void* d_out, int out_size, void* d_ws, size_t ws_size,
                              hipStream_t stream) {
    (void)in_sizes; (void)n_in; (void)out_size;
    const float* x      = (const float*)d_in[0];
    // d_in[1] = input_paddings (all zero, unused per reference)
    const float* kern   = (const float*)d_in[2];
    const float* bias   = (const float*)d_in[3];
    const float* h_init = (const float*)d_in[4];
    float* out = (float*)d_out;

    char* ws = (char*)d_ws;
    unsigned short* wt   = (unsigned short*)(ws);                       // 12,582,912 B
    unsigned short* xT   = (unsigned short*)(ws + 12582912);            // 33,554,432 B
    float*          hbuf = (float*)(ws + 12582912 + 33554432);          //    262,144 B
    (void)ws_size;

    prep_wt<<<dim3(64 * 24), dim3(256), 0, stream>>>(kern, wt);
    prep_x<<<dim3(BATCH * T_STEPS / 2), dim3(256), 0, stream>>>(x, xT);
    init_h<<<dim3(128), dim3(256), 0, stream>>>(h_init, (unsigned*)hbuf);

    void* args[] = { &wt, &xT, &hbuf, &bias, &out };
    hipLaunchCooperativeKernel((const void*)lstm_persist, dim3(NBLK), dim3(512),
                               args, 0, stream);
}